// Round 4
// baseline (417.523 us; speedup 1.0000x reference)
//
#include <hip/hip_runtime.h>

// ---------------------------------------------------------------------------
// B=4, N1=1024, N2=1024, D=256, H=4, Dh=64
//   u[b,i,4] = gelu(prev@W_pre+b_pre) @ W_fuse[0:6]
//   v[b,j,4] = gelu(curr@W_cur+b_cur) @ W_fuse[6:12] + b_fuse
//   c = mask ? u_i+v_j : 0
//   Gd_j[8] = gelu(d_j)@W_ffn[4:8] + gelu(e_j)@W_ffn[8:12] + b_ffn
//   logits = gelu(gelu(c)@W_ffn[0:4] + Gd_j)@W_fcc + b_fcc
//   softmax over i WITHOUT max-subtraction (logits bounded; masked -> exp=0)
//   res = P @ prev (per-head);  g_j = (T_j@W_ffn[0:4]+cnt*Gd_j)/(cnt+1)
//   out = res + gelu(g)@W_fcg + b_fcg
// i-range split across SPLIT blocks; partials merged in k_merge (plain sums).
// ---------------------------------------------------------------------------

__device__ __forceinline__ float gelu_f(float x){
    float x3 = x*x*x;
    float t2 = 1.5957691216057308f * (x + 0.044715f*x3);
    float e  = __expf(t2);
    return x - __fdividef(x, e + 1.0f);
}

// ---- kernel 1: per-row u (prev side) and v (curr side), one wave per row ----
__global__ __launch_bounds__(256) void k_rows(
    const float* __restrict__ prev, const float* __restrict__ curr,
    const float* __restrict__ W_pre, const float* __restrict__ b_pre,
    const float* __restrict__ W_cur, const float* __restrict__ b_cur,
    const float* __restrict__ W_fuse, const float* __restrict__ b_fuse,
    float* __restrict__ u_ws, float* __restrict__ v_ws)
{
    int gid  = blockIdx.x * 256 + threadIdx.x;
    int wave = gid >> 6;
    int lane = threadIdx.x & 63;
    bool isPrev = wave < 4096;
    int row = isPrev ? wave : (wave - 4096);
    const float* xrow = (isPrev ? prev : curr) + (size_t)row * 256;
    const float* W  = isPrev ? W_pre : W_cur;
    const float* bv = isPrev ? b_pre : b_cur;

    float4 x4 = *reinterpret_cast<const float4*>(xrow + lane*4);
    const float* Wl = W + lane*24;
    float p[6];
    #pragma unroll
    for (int k=0;k<6;++k)
        p[k] = x4.x*Wl[k] + x4.y*Wl[6+k] + x4.z*Wl[12+k] + x4.w*Wl[18+k];
    #pragma unroll
    for (int off=32; off>=1; off>>=1){
        #pragma unroll
        for (int k=0;k<6;++k) p[k] += __shfl_xor(p[k], off, 64);
    }
    if (lane == 0){
        float g[6];
        #pragma unroll
        for(int k=0;k<6;++k) g[k] = gelu_f(p[k] + bv[k]);
        int rb = isPrev ? 0 : 6;
        float o[4];
        #pragma unroll
        for(int kk=0;kk<4;++kk){
            float a = isPrev ? 0.0f : b_fuse[kk];
            #pragma unroll
            for(int k=0;k<6;++k) a += g[k]*W_fuse[(rb+k)*4+kk];
            o[kk]=a;
        }
        float* dst = (isPrev ? u_ws : v_ws) + (size_t)row*4;
        *reinterpret_cast<float4*>(dst) = make_float4(o[0],o[1],o[2],o[3]);
    }
}

// ---- kernel 2: per-column reductions over edges + Gd precompute ----
// Block = (b, 16 cols); thread (jq=t&3: 4-col quad, sl=t>>2: 16-i slice)
__global__ __launch_bounds__(256) void k_cols(
    const int* __restrict__ edges,
    const float* __restrict__ u_ws, const float* __restrict__ v_ws,
    const float* __restrict__ W_ffn, const float* __restrict__ b_ffn,
    float* __restrict__ Gd_ws, float* __restrict__ cnt_ws)
{
    int b  = blockIdx.x >> 6;
    int j0 = (blockIdx.x & 63) * 16;
    int t  = threadIdx.x;
    int jq = t & 3, sl = t >> 2;
    const int*   eb = edges + (size_t)b*1048576 + j0 + jq*4;
    const float* ub = u_ws + (size_t)b*4096;

    int   cnt[4] = {0,0,0,0};
    float S[4][4] = {{0.f}};
    float M[4][4];
    #pragma unroll
    for (int q=0;q<4;++q)
        #pragma unroll
        for (int k=0;k<4;++k) M[q][k] = -3.4e38f;

    #pragma unroll 4
    for (int ii=0; ii<16; ++ii){
        int i = sl*16 + ii;
        int4   e4 = *reinterpret_cast<const int4*>(eb + (size_t)i*1024);
        float4 u4 = *reinterpret_cast<const float4*>(ub + i*4);
        float uu[4] = {u4.x,u4.y,u4.z,u4.w};
        int   ee[4] = {e4.x,e4.y,e4.z,e4.w};
        #pragma unroll
        for (int q=0;q<4;++q){
            bool mk = ee[q]!=0;
            cnt[q] += mk ? 1 : 0;
            #pragma unroll
            for (int k=0;k<4;++k){
                S[q][k] += mk ? uu[k] : 0.0f;
                M[q][k]  = mk ? fmaxf(M[q][k],uu[k]) : M[q][k];
            }
        }
    }
    __shared__ float rS[64][16][4];
    __shared__ float rM[64][16][4];
    __shared__ int   rC[64][16];
    #pragma unroll
    for (int q=0;q<4;++q){
        int c = jq*4+q;
        #pragma unroll
        for (int k=0;k<4;++k){ rS[sl][c][k]=S[q][k]; rM[sl][c][k]=M[q][k]; }
        rC[sl][c]=cnt[q];
    }
    __syncthreads();
    float aS[4], aM[4]; int aC=0; int c2=0, hf=0;
    if (t < 128){
        c2 = t & 15; hf = t >> 4;
        #pragma unroll
        for(int k=0;k<4;++k){ aS[k]=0.f; aM[k]=-3.4e38f; }
        for (int s2=hf*8; s2<hf*8+8; ++s2){
            aC += rC[s2][c2];
            #pragma unroll
            for(int k=0;k<4;++k){ aS[k]+=rS[s2][c2][k]; aM[k]=fmaxf(aM[k],rM[s2][c2][k]); }
        }
    }
    __syncthreads();
    if (t < 128){
        rC[hf][c2]=aC;
        #pragma unroll
        for(int k=0;k<4;++k){ rS[hf][c2][k]=aS[k]; rM[hf][c2][k]=aM[k]; }
    }
    __syncthreads();
    if (t < 16){
        int cc=0; float Sa[4]={0,0,0,0};
        float Ma[4]={-3.4e38f,-3.4e38f,-3.4e38f,-3.4e38f};
        for (int s2=0;s2<8;++s2){
            cc += rC[s2][t];
            #pragma unroll
            for(int k=0;k<4;++k){ Sa[k]+=rS[s2][t][k]; Ma[k]=fmaxf(Ma[k],rM[s2][t][k]); }
        }
        size_t cj = (size_t)b*1024 + j0 + t;
        float4 v4 = *reinterpret_cast<const float4*>(v_ws + cj*4);
        float vv[4]={v4.x,v4.y,v4.z,v4.w};
        float cf = (float)cc, e1 = cf + 1.0f;
        float gd[4], ge[4];
        #pragma unroll
        for(int k=0;k<4;++k){
            float dk = (Sa[k] + cf*vv[k]) / e1;
            float ek;
            if (cc == 0) ek = 0.0f;
            else { float m1 = Ma[k]+vv[k]; ek = (cc < 1024) ? fmaxf(m1, 0.0f) : m1; }
            gd[k]=gelu_f(dk); ge[k]=gelu_f(ek);
        }
        #pragma unroll
        for(int kk=0;kk<8;++kk){
            float a = b_ffn[kk];
            #pragma unroll
            for(int k=0;k<4;++k)
                a += gd[k]*W_ffn[(4+k)*8+kk] + ge[k]*W_ffn[(8+k)*8+kk];
            Gd_ws[cj*8+kk]=a;
        }
        cnt_ws[cj]=cf;
    }
}

// ---- kernel 3: logits + exp-sum + weighted prev; writes partials ----
// Block = (b, jtile of 8 cols, sp i-half). 256 threads.
// Logit role: (il_w=t>>3, jl_w=t&7).  PV role: (dq=t&7, h=(t>>3)&3, ig=t>>5).
// No max-subtraction: masked logit = -1e30 -> expf -> 0; sums are exact-mergeable.
template<int SPLIT>
__global__ __launch_bounds__(256,4) void k_main(
    const float* __restrict__ prev, const int* __restrict__ edges,
    const float* __restrict__ u_ws, const float* __restrict__ v_ws,
    const float* __restrict__ Gd_ws,
    const float* __restrict__ W_ffn, const float* __restrict__ W_fcc,
    const float* __restrict__ b_fcc,
    float* __restrict__ Pws, float* __restrict__ Tws)
{
    int bid = blockIdx.x;
    int sp  = bid & (SPLIT-1);
    int jt  = (bid / SPLIT) & 127;
    int b   = bid / (SPLIT*128);
    int j0  = jt*8;
    int t   = threadIdx.x;
    int jl_w = t & 7, il_w = t >> 3;
    int dq = t & 7, h = (t >> 3) & 3, ig = t >> 5;

    __shared__ float sLog[64*36];    // [il][h*8+jl], stride 36 (2-way banks max)
    __shared__ float sU[64][4];
    __shared__ float sV[8][4];
    __shared__ float sGd[8][8];
    __shared__ float sMrg[4*32*37];  // merge buffer; reused as sT[32][8][4]

    if (t < 32) (&sV[0][0])[t]  = v_ws[((size_t)b*1024 + j0)*4 + t];
    if (t < 64) (&sGd[0][0])[t] = Gd_ws[((size_t)b*1024 + j0)*8 + t];

    // uniform weights -> scalar regs
    float W4r[4][8], Wfc[8][4], bfc[4];
    #pragma unroll
    for(int k=0;k<4;++k)
        #pragma unroll
        for(int kk=0;kk<8;++kk) W4r[k][kk]=W_ffn[k*8+kk];
    #pragma unroll
    for(int kk=0;kk<8;++kk)
        #pragma unroll
        for(int hh=0;hh<4;++hh) Wfc[kk][hh]=W_fcc[kk*4+hh];
    #pragma unroll
    for(int hh=0;hh<4;++hh) bfc[hh]=b_fcc[hh];

    float s[8], acc[8][8], Tp[4]={0,0,0,0};
    #pragma unroll
    for(int jl=0;jl<8;++jl){
        s[jl]=0.0f;
        #pragma unroll
        for(int d2=0;d2<8;++d2) acc[jl][d2]=0.0f;
    }

    const int*   ebase  = edges + (size_t)b*1048576 + j0;
    const float* pbBase = prev  + (size_t)b*262144 + h*64 + dq*8;

    const int NCH = 16/SPLIT;
    for (int cc=0; cc<NCH; ++cc){
        int i0 = sp*(1024/SPLIT) + cc*64;
        __syncthreads();
        (&sU[0][0])[t] = u_ws[((size_t)b*1024 + i0)*4 + t];
        __syncthreads();

        // ---- logit phase: 512 pairs, 2 per thread ----
        #pragma unroll
        for (int r=0;r<2;++r){
            int il = il_w + 32*r;
            int eg = ebase[(size_t)(i0+il)*1024 + jl_w];
            float gc[4];
            #pragma unroll
            for(int k=0;k<4;++k){
                float ccv = sU[il][k] + sV[jl_w][k];
                gc[k] = gelu_f(ccv);
                Tp[k] += eg ? gc[k] : 0.0f;
            }
            float fu[8];
            #pragma unroll
            for(int kk=0;kk<8;++kk){
                float a = sGd[jl_w][kk];
                #pragma unroll
                for(int k=0;k<4;++k) a += gc[k]*W4r[k][kk];
                fu[kk] = gelu_f(a);
            }
            #pragma unroll
            for(int hh=0;hh<4;++hh){
                float a = bfc[hh];
                #pragma unroll
                for(int kk=0;kk<8;++kk) a += fu[kk]*Wfc[kk][hh];
                sLog[il*36 + hh*8 + jl_w] = eg ? a : -1e30f;
            }
        }
        __syncthreads();

        // ---- PV: this ig's 8 rows, all 8 columns; w = exp(logit) ----
        const float* pc  = pbBase + (size_t)(i0 + ig*8)*256;
        const float* lgb = sLog + (ig*8)*36 + h*8;
        #pragma unroll
        for (int ii=0; ii<8; ++ii){
            float4 a0 = *reinterpret_cast<const float4*>(pc + ii*256);
            float4 a1 = *reinterpret_cast<const float4*>(pc + ii*256 + 4);
            const float* lg = lgb + ii*36;
            float2 w01 = *reinterpret_cast<const float2*>(lg);
            float2 w23 = *reinterpret_cast<const float2*>(lg+2);
            float2 w45 = *reinterpret_cast<const float2*>(lg+4);
            float2 w67 = *reinterpret_cast<const float2*>(lg+6);
            float l[8] = {w01.x,w01.y,w23.x,w23.y,w45.x,w45.y,w67.x,w67.y};
            #pragma unroll
            for (int jl=0;jl<8;++jl){
                float w = __expf(l[jl]);       // masked -> exp(-1e30) = 0
                s[jl] += w;
                acc[jl][0]+=w*a0.x; acc[jl][1]+=w*a0.y;
                acc[jl][2]+=w*a0.z; acc[jl][3]+=w*a0.w;
                acc[jl][4]+=w*a1.x; acc[jl][5]+=w*a1.y;
                acc[jl][6]+=w*a1.z; acc[jl][7]+=w*a1.w;
            }
        }
    }

    // ---- intra-block merge across ig (plain sums), 2 passes of 4 cols ----
    int role = t & 31;
    #pragma unroll
    for (int half=0; half<2; ++half){
        float vals[36];
        #pragma unroll
        for (int j2=0;j2<4;++j2){
            vals[j2]=s[half*4+j2];
            #pragma unroll
            for (int d2=0;d2<8;++d2) vals[4+j2*8+d2]=acc[half*4+j2][d2];
        }
        #pragma unroll
        for (int stride=4; stride>=1; stride>>=1){
            __syncthreads();
            if (ig >= stride && ig < 2*stride){
                float* dst = sMrg + (size_t)((ig-stride)*32 + role)*37;
                #pragma unroll
                for (int x=0;x<36;++x) dst[x]=vals[x];
            }
            __syncthreads();
            if (ig < stride){
                const float* src = sMrg + (size_t)(ig*32 + role)*37;
                #pragma unroll
                for (int x=0;x<36;++x) vals[x]+=src[x];
            }
        }
        if (ig==0){
            #pragma unroll
            for (int j2=0;j2<4;++j2){
                s[half*4+j2]=vals[j2];
                #pragma unroll
                for (int d2=0;d2<8;++d2) acc[half*4+j2][d2]=vals[4+j2*8+d2];
            }
        }
    }

    size_t bp = ((size_t)b*128 + jt)*SPLIT + sp;

    // ---- T reduction (sMrg reused as sT[32][8][4]) ----
    __syncthreads();
    float* sT = sMrg;
    #pragma unroll
    for (int k=0;k<4;++k) sT[(il_w*8 + jl_w)*4 + k] = Tp[k];
    __syncthreads();
    if (t < 8){
        float T0=0,T1=0,T2=0,T3=0;
        for (int s2=0;s2<32;++s2){
            const float* p = sT + (s2*8+t)*4;
            T0+=p[0];T1+=p[1];T2+=p[2];T3+=p[3];
        }
        float* td = Tws + (bp*8 + t)*4;
        td[0]=T0; td[1]=T1; td[2]=T2; td[3]=T3;
    }
    if (t < 32){
        float* dst = Pws + (bp*32 + t)*72;
        #pragma unroll
        for (int jl=0;jl<8;++jl){
            dst[jl*9]=s[jl];
            #pragma unroll
            for (int d2=0;d2<8;++d2) dst[jl*9+1+d2]=acc[jl][d2];
        }
    }
}

// ---- kernel 4: merge split partials, normalize, add gelu(g)@W_fcg ----
// Block = (b, jtile of 8 cols). Thread: jl=t>>5, hd=t&31 (h=hd>>3, dq=hd&7).
template<int SPLIT>
__global__ __launch_bounds__(256) void k_merge(
    const float* __restrict__ Pws, const float* __restrict__ Tws,
    const float* __restrict__ Gd_ws, const float* __restrict__ cnt_ws,
    const float* __restrict__ W_ffn, const float* __restrict__ W_fcg,
    const float* __restrict__ b_fcg, float* __restrict__ out)
{
    int b  = blockIdx.x >> 7;
    int jt = blockIdx.x & 127;
    int j0 = jt*8;
    int t  = threadIdx.x;
    int jl = t >> 5, hd = t & 31, h = hd >> 3, dq = hd & 7;
    __shared__ float sG[8][8];

    size_t bp0 = ((size_t)b*128 + jt)*SPLIT;
    float s = 0.0f, acc[8] = {0,0,0,0,0,0,0,0};
    #pragma unroll
    for (int sp2=0; sp2<SPLIT; ++sp2){
        const float* p = Pws + ((bp0+sp2)*32 + hd)*72 + jl*9;
        s += p[0];
        #pragma unroll
        for (int d2=0;d2<8;++d2) acc[d2] += p[1+d2];
    }
    if (t < 8){
        float T[4] = {0,0,0,0};
        #pragma unroll
        for (int sp2=0; sp2<SPLIT; ++sp2){
            const float* tp = Tws + ((bp0+sp2)*8 + t)*4;
            #pragma unroll
            for (int k=0;k<4;++k) T[k]+=tp[k];
        }
        size_t cj = (size_t)b*1024 + j0 + t;
        float cf = cnt_ws[cj];
        float inv = __fdividef(1.0f, cf + 1.0f);
        #pragma unroll
        for (int kk=0;kk<8;++kk){
            float a = cf*Gd_ws[cj*8+kk];
            #pragma unroll
            for (int k=0;k<4;++k) a += T[k]*W_ffn[k*8+kk];
            sG[t][kk] = gelu_f(a*inv);
        }
    }
    __syncthreads();

    float rs = (s > 0.0f) ? (1.0f/s) : 0.0f;
    int col0 = h*64 + dq*8;
    float gg[8];
    #pragma unroll
    for (int kk=0;kk<8;++kk) gg[kk]=sG[jl][kk];
    float o[8];
    #pragma unroll
    for (int d2=0;d2<8;++d2){
        float a = b_fcg[col0+d2];
        #pragma unroll
        for (int kk=0;kk<8;++kk) a += gg[kk]*W_fcg[kk*256 + col0 + d2];
        o[d2] = acc[d2]*rs + a;
    }
    float* ob = out + ((size_t)b*1024 + j0 + jl)*256 + col0;
    float4* o4 = reinterpret_cast<float4*>(ob);
    o4[0] = make_float4(o[0],o[1],o[2],o[3]);
    o4[1] = make_float4(o[4],o[5],o[6],o[7]);
}

extern "C" void kernel_launch(void* const* d_in, const int* in_sizes, int n_in,
                              void* d_out, int out_size, void* d_ws, size_t ws_size,
                              hipStream_t stream)
{
    const float* prev  = (const float*)d_in[0];
    const float* curr  = (const float*)d_in[1];
    const int*   edges = (const int*)  d_in[2];
    const float* W_pre = (const float*)d_in[3];
    const float* b_pre = (const float*)d_in[4];
    const float* W_cur = (const float*)d_in[5];
    const float* b_cur = (const float*)d_in[6];
    const float* W_fuse= (const float*)d_in[7];
    const float* b_fuse= (const float*)d_in[8];
    const float* W_ffn = (const float*)d_in[9];
    const float* b_ffn = (const float*)d_in[10];
    const float* b_fcc = (const float*)d_in[12];
    const float* W_fcc = (const float*)d_in[11];
    const float* W_fcg = (const float*)d_in[13];
    const float* b_fcg = (const float*)d_in[14];
    float* out = (float*)d_out;

    float* u_ws   = (float*)d_ws;          // 16384 floats
    float* v_ws   = u_ws  + 16384;         // 16384
    float* Gd_ws  = v_ws  + 16384;         // 32768
    float* cnt_ws = Gd_ws + 32768;         // 4096
    float* Pws    = cnt_ws + 4096;
    const size_t base_f = 16384 + 16384 + 32768 + 4096;
    const size_t p2 = (size_t)4*128*2*32*72, t2 = (size_t)4*128*2*8*4;
    const size_t need2 = (base_f + p2 + t2) * 4;

    k_rows<<<dim3(2048), dim3(256), 0, stream>>>(prev, curr, W_pre, b_pre,
        W_cur, b_cur, W_fuse, b_fuse, u_ws, v_ws);
    k_cols<<<dim3(256), dim3(256), 0, stream>>>(edges, u_ws, v_ws,
        W_ffn, b_ffn, Gd_ws, cnt_ws);

    if (ws_size >= need2){
        float* Tws = Pws + p2;
        k_main<2><<<dim3(1024), dim3(256), 0, stream>>>(prev, edges, u_ws, v_ws,
            Gd_ws, W_ffn, W_fcc, b_fcc, Pws, Tws);
        k_merge<2><<<dim3(512), dim3(256), 0, stream>>>(Pws, Tws, Gd_ws, cnt_ws,
            W_ffn, W_fcg, b_fcg, out);
    } else {
        float* Tws = Pws + (size_t)4*128*1*32*72;
        k_main<1><<<dim3(512), dim3(256), 0, stream>>>(prev, edges, u_ws, v_ws,
            Gd_ws, W_ffn, W_fcc, b_fcc, Pws, Tws);
        k_merge<1><<<dim3(512), dim3(256), 0, stream>>>(Pws, Tws, Gd_ws, cnt_ws,
            W_ffn, W_fcg, b_fcg, out);
    }
}

// Round 5
// 145.387 us; speedup vs baseline: 2.8718x; 2.8718x over previous
//
#include <hip/hip_runtime.h>

// ---------------------------------------------------------------------------
// B=4, N1=1024, N2=1024, D=256, H=4, Dh=64
//   u[b,i,4] = gelu(prev@W_pre+b_pre) @ W_fuse[0:6]
//   v[b,j,4] = gelu(curr@W_cur+b_cur) @ W_fuse[6:12] + b_fuse
//   c = mask ? u_i+v_j : 0
//   Gd_j[8] = gelu(d_j)@W_ffn[4:8] + gelu(e_j)@W_ffn[8:12] + b_ffn
//   logits = gelu(gelu(c)@W_ffn[0:4] + Gd_j)@W_fcc + b_fcc
//   softmax over i WITHOUT max-subtraction (logits bounded; masked -> exp=0)
//   res = P @ prev (per-head);  g_j = (T_j@W_ffn[0:4]+cnt*Gd_j)/(cnt+1)
//   out = res + gelu(g)@W_fcg + b_fcg
// i-range split across SPLIT blocks; partials merged in k_merge (plain sums).
// NOTE: k_main uses plain __launch_bounds__(256). Round-4 lesson: (256,4)
// forced VGPR->64 and spilled ~1.9GB of scratch to HBM (400us regression).
// ---------------------------------------------------------------------------

__device__ __forceinline__ float gelu_f(float x){
    float x3 = x*x*x;
    float t2 = 1.5957691216057308f * (x + 0.044715f*x3);
    float e  = __expf(t2);
    return x - __fdividef(x, e + 1.0f);
}

// ---- kernel 1: per-row u (prev side) and v (curr side), one wave per row ----
__global__ __launch_bounds__(256) void k_rows(
    const float* __restrict__ prev, const float* __restrict__ curr,
    const float* __restrict__ W_pre, const float* __restrict__ b_pre,
    const float* __restrict__ W_cur, const float* __restrict__ b_cur,
    const float* __restrict__ W_fuse, const float* __restrict__ b_fuse,
    float* __restrict__ u_ws, float* __restrict__ v_ws)
{
    int gid  = blockIdx.x * 256 + threadIdx.x;
    int wave = gid >> 6;
    int lane = threadIdx.x & 63;
    bool isPrev = wave < 4096;
    int row = isPrev ? wave : (wave - 4096);
    const float* xrow = (isPrev ? prev : curr) + (size_t)row * 256;
    const float* W  = isPrev ? W_pre : W_cur;
    const float* bv = isPrev ? b_pre : b_cur;

    float4 x4 = *reinterpret_cast<const float4*>(xrow + lane*4);
    const float* Wl = W + lane*24;
    float p[6];
    #pragma unroll
    for (int k=0;k<6;++k)
        p[k] = x4.x*Wl[k] + x4.y*Wl[6+k] + x4.z*Wl[12+k] + x4.w*Wl[18+k];
    #pragma unroll
    for (int off=32; off>=1; off>>=1){
        #pragma unroll
        for (int k=0;k<6;++k) p[k] += __shfl_xor(p[k], off, 64);
    }
    if (lane == 0){
        float g[6];
        #pragma unroll
        for(int k=0;k<6;++k) g[k] = gelu_f(p[k] + bv[k]);
        int rb = isPrev ? 0 : 6;
        float o[4];
        #pragma unroll
        for(int kk=0;kk<4;++kk){
            float a = isPrev ? 0.0f : b_fuse[kk];
            #pragma unroll
            for(int k=0;k<6;++k) a += g[k]*W_fuse[(rb+k)*4+kk];
            o[kk]=a;
        }
        float* dst = (isPrev ? u_ws : v_ws) + (size_t)row*4;
        *reinterpret_cast<float4*>(dst) = make_float4(o[0],o[1],o[2],o[3]);
    }
}

// ---- kernel 2: per-column reductions over edges + Gd precompute ----
// Block = (b, 16 cols); thread (jq=t&3: 4-col quad, sl=t>>2: 16-i slice)
__global__ __launch_bounds__(256) void k_cols(
    const int* __restrict__ edges,
    const float* __restrict__ u_ws, const float* __restrict__ v_ws,
    const float* __restrict__ W_ffn, const float* __restrict__ b_ffn,
    float* __restrict__ Gd_ws, float* __restrict__ cnt_ws)
{
    int b  = blockIdx.x >> 6;
    int j0 = (blockIdx.x & 63) * 16;
    int t  = threadIdx.x;
    int jq = t & 3, sl = t >> 2;
    const int*   eb = edges + (size_t)b*1048576 + j0 + jq*4;
    const float* ub = u_ws + (size_t)b*4096;

    int   cnt[4] = {0,0,0,0};
    float S[4][4] = {{0.f}};
    float M[4][4];
    #pragma unroll
    for (int q=0;q<4;++q)
        #pragma unroll
        for (int k=0;k<4;++k) M[q][k] = -3.4e38f;

    #pragma unroll 4
    for (int ii=0; ii<16; ++ii){
        int i = sl*16 + ii;
        int4   e4 = *reinterpret_cast<const int4*>(eb + (size_t)i*1024);
        float4 u4 = *reinterpret_cast<const float4*>(ub + i*4);
        float uu[4] = {u4.x,u4.y,u4.z,u4.w};
        int   ee[4] = {e4.x,e4.y,e4.z,e4.w};
        #pragma unroll
        for (int q=0;q<4;++q){
            bool mk = ee[q]!=0;
            cnt[q] += mk ? 1 : 0;
            #pragma unroll
            for (int k=0;k<4;++k){
                S[q][k] += mk ? uu[k] : 0.0f;
                M[q][k]  = mk ? fmaxf(M[q][k],uu[k]) : M[q][k];
            }
        }
    }
    __shared__ float rS[64][16][4];
    __shared__ float rM[64][16][4];
    __shared__ int   rC[64][16];
    #pragma unroll
    for (int q=0;q<4;++q){
        int c = jq*4+q;
        #pragma unroll
        for (int k=0;k<4;++k){ rS[sl][c][k]=S[q][k]; rM[sl][c][k]=M[q][k]; }
        rC[sl][c]=cnt[q];
    }
    __syncthreads();
    float aS[4], aM[4]; int aC=0; int c2=0, hf=0;
    if (t < 128){
        c2 = t & 15; hf = t >> 4;
        #pragma unroll
        for(int k=0;k<4;++k){ aS[k]=0.f; aM[k]=-3.4e38f; }
        for (int s2=hf*8; s2<hf*8+8; ++s2){
            aC += rC[s2][c2];
            #pragma unroll
            for(int k=0;k<4;++k){ aS[k]+=rS[s2][c2][k]; aM[k]=fmaxf(aM[k],rM[s2][c2][k]); }
        }
    }
    __syncthreads();
    if (t < 128){
        rC[hf][c2]=aC;
        #pragma unroll
        for(int k=0;k<4;++k){ rS[hf][c2][k]=aS[k]; rM[hf][c2][k]=aM[k]; }
    }
    __syncthreads();
    if (t < 16){
        int cc=0; float Sa[4]={0,0,0,0};
        float Ma[4]={-3.4e38f,-3.4e38f,-3.4e38f,-3.4e38f};
        for (int s2=0;s2<8;++s2){
            cc += rC[s2][t];
            #pragma unroll
            for(int k=0;k<4;++k){ Sa[k]+=rS[s2][t][k]; Ma[k]=fmaxf(Ma[k],rM[s2][t][k]); }
        }
        size_t cj = (size_t)b*1024 + j0 + t;
        float4 v4 = *reinterpret_cast<const float4*>(v_ws + cj*4);
        float vv[4]={v4.x,v4.y,v4.z,v4.w};
        float cf = (float)cc, e1 = cf + 1.0f;
        float gd[4], ge[4];
        #pragma unroll
        for(int k=0;k<4;++k){
            float dk = (Sa[k] + cf*vv[k]) / e1;
            float ek;
            if (cc == 0) ek = 0.0f;
            else { float m1 = Ma[k]+vv[k]; ek = (cc < 1024) ? fmaxf(m1, 0.0f) : m1; }
            gd[k]=gelu_f(dk); ge[k]=gelu_f(ek);
        }
        #pragma unroll
        for(int kk=0;kk<8;++kk){
            float a = b_ffn[kk];
            #pragma unroll
            for(int k=0;k<4;++k)
                a += gd[k]*W_ffn[(4+k)*8+kk] + ge[k]*W_ffn[(8+k)*8+kk];
            Gd_ws[cj*8+kk]=a;
        }
        cnt_ws[cj]=cf;
    }
}

// ---- kernel 3: logits + exp-sum + weighted prev; writes partials ----
// Block = (b, jtile of 8 cols, sp i-half). 256 threads.
// Logit role: (il_w=t>>3, jl_w=t&7).  PV role: (dq=t&7, h=(t>>3)&3, ig=t>>5).
// No max-subtraction: masked logit = -1e30 -> expf -> 0; sums are exact-mergeable.
template<int SPLIT>
__global__ __launch_bounds__(256) void k_main(
    const float* __restrict__ prev, const int* __restrict__ edges,
    const float* __restrict__ u_ws, const float* __restrict__ v_ws,
    const float* __restrict__ Gd_ws,
    const float* __restrict__ W_ffn, const float* __restrict__ W_fcc,
    const float* __restrict__ b_fcc,
    float* __restrict__ Pws, float* __restrict__ Tws)
{
    int bid = blockIdx.x;
    int sp  = bid & (SPLIT-1);
    int jt  = (bid / SPLIT) & 127;
    int b   = bid / (SPLIT*128);
    int j0  = jt*8;
    int t   = threadIdx.x;
    int jl_w = t & 7, il_w = t >> 3;
    int dq = t & 7, h = (t >> 3) & 3, ig = t >> 5;

    __shared__ float sLog[64*36];    // [il][h*8+jl], stride 36 (2-way banks max)
    __shared__ float sU[64][4];
    __shared__ float sV[8][4];
    __shared__ float sGd[8][8];
    __shared__ float sMrg[4*32*37];  // merge buffer; reused as sT[32][8][4]

    if (t < 32) (&sV[0][0])[t]  = v_ws[((size_t)b*1024 + j0)*4 + t];
    if (t < 64) (&sGd[0][0])[t] = Gd_ws[((size_t)b*1024 + j0)*8 + t];

    // uniform weights -> scalar regs
    float W4r[4][8], Wfc[8][4], bfc[4];
    #pragma unroll
    for(int k=0;k<4;++k)
        #pragma unroll
        for(int kk=0;kk<8;++kk) W4r[k][kk]=W_ffn[k*8+kk];
    #pragma unroll
    for(int kk=0;kk<8;++kk)
        #pragma unroll
        for(int hh=0;hh<4;++hh) Wfc[kk][hh]=W_fcc[kk*4+hh];
    #pragma unroll
    for(int hh=0;hh<4;++hh) bfc[hh]=b_fcc[hh];

    float s[8], acc[8][8], Tp[4]={0,0,0,0};
    #pragma unroll
    for(int jl=0;jl<8;++jl){
        s[jl]=0.0f;
        #pragma unroll
        for(int d2=0;d2<8;++d2) acc[jl][d2]=0.0f;
    }

    const int*   ebase  = edges + (size_t)b*1048576 + j0;
    const float* pbBase = prev  + (size_t)b*262144 + h*64 + dq*8;

    const int NCH = 16/SPLIT;
    for (int cc=0; cc<NCH; ++cc){
        int i0 = sp*(1024/SPLIT) + cc*64;
        __syncthreads();
        (&sU[0][0])[t] = u_ws[((size_t)b*1024 + i0)*4 + t];
        __syncthreads();

        // ---- logit phase: 512 pairs, 2 per thread ----
        #pragma unroll
        for (int r=0;r<2;++r){
            int il = il_w + 32*r;
            int eg = ebase[(size_t)(i0+il)*1024 + jl_w];
            float gc[4];
            #pragma unroll
            for(int k=0;k<4;++k){
                float ccv = sU[il][k] + sV[jl_w][k];
                gc[k] = gelu_f(ccv);
                Tp[k] += eg ? gc[k] : 0.0f;
            }
            float fu[8];
            #pragma unroll
            for(int kk=0;kk<8;++kk){
                float a = sGd[jl_w][kk];
                #pragma unroll
                for(int k=0;k<4;++k) a += gc[k]*W4r[k][kk];
                fu[kk] = gelu_f(a);
            }
            #pragma unroll
            for(int hh=0;hh<4;++hh){
                float a = bfc[hh];
                #pragma unroll
                for(int kk=0;kk<8;++kk) a += fu[kk]*Wfc[kk][hh];
                sLog[il*36 + hh*8 + jl_w] = eg ? a : -1e30f;
            }
        }
        __syncthreads();

        // ---- PV: this ig's 8 rows, all 8 columns; w = exp(logit) ----
        const float* pc  = pbBase + (size_t)(i0 + ig*8)*256;
        const float* lgb = sLog + (ig*8)*36 + h*8;
        #pragma unroll
        for (int ii=0; ii<8; ++ii){
            float4 a0 = *reinterpret_cast<const float4*>(pc + ii*256);
            float4 a1 = *reinterpret_cast<const float4*>(pc + ii*256 + 4);
            const float* lg = lgb + ii*36;
            float2 w01 = *reinterpret_cast<const float2*>(lg);
            float2 w23 = *reinterpret_cast<const float2*>(lg+2);
            float2 w45 = *reinterpret_cast<const float2*>(lg+4);
            float2 w67 = *reinterpret_cast<const float2*>(lg+6);
            float l[8] = {w01.x,w01.y,w23.x,w23.y,w45.x,w45.y,w67.x,w67.y};
            #pragma unroll
            for (int jl=0;jl<8;++jl){
                float w = __expf(l[jl]);       // masked -> exp(-1e30) = 0
                s[jl] += w;
                acc[jl][0]+=w*a0.x; acc[jl][1]+=w*a0.y;
                acc[jl][2]+=w*a0.z; acc[jl][3]+=w*a0.w;
                acc[jl][4]+=w*a1.x; acc[jl][5]+=w*a1.y;
                acc[jl][6]+=w*a1.z; acc[jl][7]+=w*a1.w;
            }
        }
    }

    // ---- intra-block merge across ig (plain sums), 2 passes of 4 cols ----
    int role = t & 31;
    #pragma unroll
    for (int half=0; half<2; ++half){
        float vals[36];
        #pragma unroll
        for (int j2=0;j2<4;++j2){
            vals[j2]=s[half*4+j2];
            #pragma unroll
            for (int d2=0;d2<8;++d2) vals[4+j2*8+d2]=acc[half*4+j2][d2];
        }
        #pragma unroll
        for (int stride=4; stride>=1; stride>>=1){
            __syncthreads();
            if (ig >= stride && ig < 2*stride){
                float* dst = sMrg + (size_t)((ig-stride)*32 + role)*37;
                #pragma unroll
                for (int x=0;x<36;++x) dst[x]=vals[x];
            }
            __syncthreads();
            if (ig < stride){
                const float* src = sMrg + (size_t)(ig*32 + role)*37;
                #pragma unroll
                for (int x=0;x<36;++x) vals[x]+=src[x];
            }
        }
        if (ig==0){
            #pragma unroll
            for (int j2=0;j2<4;++j2){
                s[half*4+j2]=vals[j2];
                #pragma unroll
                for (int d2=0;d2<8;++d2) acc[half*4+j2][d2]=vals[4+j2*8+d2];
            }
        }
    }

    size_t bp = ((size_t)b*128 + jt)*SPLIT + sp;

    // ---- T reduction (sMrg reused as sT[32][8][4]) ----
    __syncthreads();
    float* sT = sMrg;
    #pragma unroll
    for (int k=0;k<4;++k) sT[(il_w*8 + jl_w)*4 + k] = Tp[k];
    __syncthreads();
    if (t < 8){
        float T0=0,T1=0,T2=0,T3=0;
        for (int s2=0;s2<32;++s2){
            const float* p = sT + (s2*8+t)*4;
            T0+=p[0];T1+=p[1];T2+=p[2];T3+=p[3];
        }
        float* td = Tws + (bp*8 + t)*4;
        td[0]=T0; td[1]=T1; td[2]=T2; td[3]=T3;
    }
    if (t < 32){
        float* dst = Pws + (bp*32 + t)*72;
        #pragma unroll
        for (int jl=0;jl<8;++jl){
            dst[jl*9]=s[jl];
            #pragma unroll
            for (int d2=0;d2<8;++d2) dst[jl*9+1+d2]=acc[jl][d2];
        }
    }
}

// ---- kernel 4: merge split partials, normalize, add gelu(g)@W_fcg ----
// Block = (b, jtile of 8 cols). Thread: jl=t>>5, hd=t&31 (h=hd>>3, dq=hd&7).
template<int SPLIT>
__global__ __launch_bounds__(256) void k_merge(
    const float* __restrict__ Pws, const float* __restrict__ Tws,
    const float* __restrict__ Gd_ws, const float* __restrict__ cnt_ws,
    const float* __restrict__ W_ffn, const float* __restrict__ W_fcg,
    const float* __restrict__ b_fcg, float* __restrict__ out)
{
    int b  = blockIdx.x >> 7;
    int jt = blockIdx.x & 127;
    int j0 = jt*8;
    int t  = threadIdx.x;
    int jl = t >> 5, hd = t & 31, h = hd >> 3, dq = hd & 7;
    __shared__ float sG[8][8];

    size_t bp0 = ((size_t)b*128 + jt)*SPLIT;
    float s = 0.0f, acc[8] = {0,0,0,0,0,0,0,0};
    #pragma unroll
    for (int sp2=0; sp2<SPLIT; ++sp2){
        const float* p = Pws + ((bp0+sp2)*32 + hd)*72 + jl*9;
        s += p[0];
        #pragma unroll
        for (int d2=0;d2<8;++d2) acc[d2] += p[1+d2];
    }
    if (t < 8){
        float T[4] = {0,0,0,0};
        #pragma unroll
        for (int sp2=0; sp2<SPLIT; ++sp2){
            const float* tp = Tws + ((bp0+sp2)*8 + t)*4;
            #pragma unroll
            for (int k=0;k<4;++k) T[k]+=tp[k];
        }
        size_t cj = (size_t)b*1024 + j0 + t;
        float cf = cnt_ws[cj];
        float inv = __fdividef(1.0f, cf + 1.0f);
        #pragma unroll
        for (int kk=0;kk<8;++kk){
            float a = cf*Gd_ws[cj*8+kk];
            #pragma unroll
            for (int k=0;k<4;++k) a += T[k]*W_ffn[k*8+kk];
            sG[t][kk] = gelu_f(a*inv);
        }
    }
    __syncthreads();

    float rs = (s > 0.0f) ? (1.0f/s) : 0.0f;
    int col0 = h*64 + dq*8;
    float gg[8];
    #pragma unroll
    for (int kk=0;kk<8;++kk) gg[kk]=sG[jl][kk];
    float o[8];
    #pragma unroll
    for (int d2=0;d2<8;++d2){
        float a = b_fcg[col0+d2];
        #pragma unroll
        for (int kk=0;kk<8;++kk) a += gg[kk]*W_fcg[kk*256 + col0 + d2];
        o[d2] = acc[d2]*rs + a;
    }
    float* ob = out + ((size_t)b*1024 + j0 + jl)*256 + col0;
    float4* o4 = reinterpret_cast<float4*>(ob);
    o4[0] = make_float4(o[0],o[1],o[2],o[3]);
    o4[1] = make_float4(o[4],o[5],o[6],o[7]);
}

extern "C" void kernel_launch(void* const* d_in, const int* in_sizes, int n_in,
                              void* d_out, int out_size, void* d_ws, size_t ws_size,
                              hipStream_t stream)
{
    const float* prev  = (const float*)d_in[0];
    const float* curr  = (const float*)d_in[1];
    const int*   edges = (const int*)  d_in[2];
    const float* W_pre = (const float*)d_in[3];
    const float* b_pre = (const float*)d_in[4];
    const float* W_cur = (const float*)d_in[5];
    const float* b_cur = (const float*)d_in[6];
    const float* W_fuse= (const float*)d_in[7];
    const float* b_fuse= (const float*)d_in[8];
    const float* W_ffn = (const float*)d_in[9];
    const float* b_ffn = (const float*)d_in[10];
    const float* b_fcc = (const float*)d_in[12];
    const float* W_fcc = (const float*)d_in[11];
    const float* W_fcg = (const float*)d_in[13];
    const float* b_fcg = (const float*)d_in[14];
    float* out = (float*)d_out;

    float* u_ws   = (float*)d_ws;          // 16384 floats
    float* v_ws   = u_ws  + 16384;         // 16384
    float* Gd_ws  = v_ws  + 16384;         // 32768
    float* cnt_ws = Gd_ws + 32768;         // 4096
    float* Pws    = cnt_ws + 4096;
    const size_t base_f = 16384 + 16384 + 32768 + 4096;
    const size_t p2 = (size_t)4*128*2*32*72, t2 = (size_t)4*128*2*8*4;
    const size_t need2 = (base_f + p2 + t2) * 4;

    k_rows<<<dim3(2048), dim3(256), 0, stream>>>(prev, curr, W_pre, b_pre,
        W_cur, b_cur, W_fuse, b_fuse, u_ws, v_ws);
    k_cols<<<dim3(256), dim3(256), 0, stream>>>(edges, u_ws, v_ws,
        W_ffn, b_ffn, Gd_ws, cnt_ws);

    if (ws_size >= need2){
        float* Tws = Pws + p2;
        k_main<2><<<dim3(1024), dim3(256), 0, stream>>>(prev, edges, u_ws, v_ws,
            Gd_ws, W_ffn, W_fcc, b_fcc, Pws, Tws);
        k_merge<2><<<dim3(512), dim3(256), 0, stream>>>(Pws, Tws, Gd_ws, cnt_ws,
            W_ffn, W_fcg, b_fcg, out);
    } else {
        float* Tws = Pws + (size_t)4*128*1*32*72;
        k_main<1><<<dim3(512), dim3(256), 0, stream>>>(prev, edges, u_ws, v_ws,
            Gd_ws, W_ffn, W_fcc, b_fcc, Pws, Tws);
        k_merge<1><<<dim3(512), dim3(256), 0, stream>>>(Pws, Tws, Gd_ws, cnt_ws,
            W_ffn, W_fcg, b_fcg, out);
    }
}